// Round 1
// baseline (121.585 us; speedup 1.0000x reference)
//
#include <hip/hip_runtime.h>

#define BB 2048
#define DD 4096
#define PP 64
#define KK 64
#define EE 8
#define C2 128

typedef __attribute__((ext_vector_type(8))) short short8;
typedef __attribute__((ext_vector_type(4))) float floatx4;

__device__ inline unsigned short f2bf(float f) {
    unsigned int u = __builtin_bit_cast(unsigned int, f);
    u += 0x7FFFu + ((u >> 16) & 1u);   // RNE round to bf16
    return (unsigned short)(u >> 16);
}

// One block per batch row b. Phases:
//  1) stage x[b] (64x64 fp32) in LDS
//  2) router: column sums -> select[8] -> gate/argmax -> select0 out + ws stage
//  3) stage selected expert weights as bf16 in LDS
//  4) MFMA 64x64 @ 64x128, epilogue (+bias)^3 summed per half -> softmax(2)
__global__ __launch_bounds__(256) void moe_fused(
    const float* __restrict__ x, const float* __restrict__ rw,
    const float* __restrict__ ew, const float* __restrict__ eb,
    float* __restrict__ out, float* __restrict__ ws_sel)
{
    __shared__ __align__(16) float patf[64][68];          // +4 pad: bank rotate, keeps 16B align
    __shared__ __align__(16) unsigned short wbf[128][72]; // 144B rows, 16B aligned
    __shared__ float biasf[128];
    __shared__ float s_col[64];
    __shared__ float sel[8];
    __shared__ float red0[4], red1[4];
    __shared__ float gate_s;
    __shared__ int idx_s;

    const int b = blockIdx.x;
    const int tid = threadIdx.x;
    const float* xb = x + (size_t)b * DD;

    // ---- phase 1: load x[b] coalesced (float4), store to padded LDS
    #pragma unroll
    for (int j = 0; j < 4; ++j) {
        int idx = j * 256 + tid;            // float4 index within 1024
        float4 v = ((const float4*)xb)[idx];
        int p = idx >> 4;
        int k = (idx & 15) << 2;
        patf[p][k + 0] = v.x; patf[p][k + 1] = v.y;
        patf[p][k + 2] = v.z; patf[p][k + 3] = v.w;
    }
    __syncthreads();

    // ---- phase 2: router (fp32 throughout: argmax must match np ref)
    if (tid < 64) {
        float s = 0.f;
        #pragma unroll
        for (int p = 0; p < 64; ++p) s += patf[p][tid];
        s_col[tid] = s;
    }
    __syncthreads();
    if (tid < 8) {
        float d = 0.f;
        const float* r = rw + tid * KK;
        #pragma unroll
        for (int k = 0; k < 64; ++k) d += s_col[k] * r[k];
        sel[tid] = d;
    }
    __syncthreads();
    if (tid == 0) {
        float g = sel[0]; int ix = 0;
        #pragma unroll
        for (int e2 = 1; e2 < 8; ++e2) { if (sel[e2] > g) { g = sel[e2]; ix = e2; } }
        gate_s = g; idx_s = ix;
    }
    __syncthreads();
    const int e = idx_s;
    const float gate = gate_s;
    if (tid < 8) {
        ws_sel[b * 8 + tid] = sel[tid];                       // staged for loss kernel
        out[BB * 2 + b * 8 + tid] = (tid == e && gate != 0.f) ? 1.f : 0.f;  // select0
    }

    // ---- phase 3: stage selected expert weights (fp32 -> bf16) + bias
    const float* we = ew + (size_t)e * (C2 * KK);
    #pragma unroll
    for (int j = 0; j < 8; ++j) {
        int idx = j * 256 + tid;            // float4 index within 2048
        float4 v = ((const float4*)we)[idx];
        int c = idx >> 4;
        int k = (idx & 15) << 2;
        wbf[c][k + 0] = f2bf(v.x); wbf[c][k + 1] = f2bf(v.y);
        wbf[c][k + 2] = f2bf(v.z); wbf[c][k + 3] = f2bf(v.w);
    }
    if (tid < 128) biasf[tid] = eb[e * C2 + tid];
    __syncthreads();

    // ---- phase 4: D[p][c] = sum_k pat[p][k] * w[c][k] via mfma 16x16x32 bf16
    const int w = tid >> 6;       // wave id -> M block (16 rows of p)
    const int lane = tid & 63;
    const int r = lane & 15;
    const int q = lane >> 4;

    floatx4 acc[8];
    #pragma unroll
    for (int nt = 0; nt < 8; ++nt) acc[nt] = (floatx4){0.f, 0.f, 0.f, 0.f};

    #pragma unroll
    for (int kb = 0; kb < 2; ++kb) {
        const int k0 = kb * 32 + q * 8;
        short8 a;
        const float* ar = &patf[w * 16 + r][k0];
        #pragma unroll
        for (int j = 0; j < 8; ++j) a[j] = (short)f2bf(ar[j]);
        #pragma unroll
        for (int nt = 0; nt < 8; ++nt) {
            short8 bfr = *(const short8*)&wbf[nt * 16 + r][k0];
            acc[nt] = __builtin_amdgcn_mfma_f32_16x16x32_bf16(a, bfr, acc[nt], 0, 0, 0);
        }
    }

    // ---- epilogue: (z + bias)^3, split halves c<64 / c>=64 (nt<4 / nt>=4)
    float h0 = 0.f, h1 = 0.f;
    #pragma unroll
    for (int nt = 0; nt < 8; ++nt) {
        float bs = biasf[nt * 16 + r];     // c = nt*16 + (lane&15)
        #pragma unroll
        for (int i = 0; i < 4; ++i) {
            float z = acc[nt][i] + bs;
            float z3 = z * z * z;
            if (nt < 4) h0 += z3; else h1 += z3;
        }
    }
    #pragma unroll
    for (int off = 32; off > 0; off >>= 1) {
        h0 += __shfl_down(h0, off);
        h1 += __shfl_down(h1, off);
    }
    if (lane == 0) { red0[w] = h0; red1[w] = h1; }
    __syncthreads();
    if (tid == 0) {
        float t0 = red0[0] + red0[1] + red0[2] + red0[3];
        float t1 = red1[0] + red1[1] + red1[2] + red1[3];
        float l0 = gate * t0, l1 = gate * t1;
        float m = fmaxf(l0, l1);
        float e0 = __expf(l0 - m), e1 = __expf(l1 - m);
        float inv = 1.f / (e0 + e1);
        out[b * 2 + 0] = e0 * inv;
        out[b * 2 + 1] = e1 * inv;
    }
}

// loss = E * sum_e (mean_b select[b,e]) * (count_b(argmax==e)/B)
__global__ __launch_bounds__(256) void loss_kernel(
    const float* __restrict__ ws_sel, float* __restrict__ out)
{
    __shared__ float sp[8];
    __shared__ float sc[8];
    const int t = threadIdx.x;
    if (t < 8) { sp[t] = 0.f; sc[t] = 0.f; }
    __syncthreads();
    float p[8] = {0, 0, 0, 0, 0, 0, 0, 0};
    float c[8] = {0, 0, 0, 0, 0, 0, 0, 0};
    for (int b = t; b < BB; b += 256) {
        const float* row = ws_sel + b * 8;
        float g = row[0]; int ix = 0;
        #pragma unroll
        for (int e2 = 0; e2 < 8; ++e2) {
            float v = row[e2];
            p[e2] += v;
            if (e2 > 0 && v > g) { g = v; ix = e2; }  // strict >: first-max, matches jnp.argmax
        }
        c[ix] += 1.f;
    }
    #pragma unroll
    for (int e2 = 0; e2 < 8; ++e2) {
        atomicAdd(&sp[e2], p[e2]);
        atomicAdd(&sc[e2], c[e2]);
    }
    __syncthreads();
    if (t == 0) {
        float loss = 0.f;
        #pragma unroll
        for (int e2 = 0; e2 < 8; ++e2)
            loss += (sp[e2] / (float)BB) * (sc[e2] / (float)BB);
        out[BB * 2 + BB * 8] = loss * (float)EE;
    }
}

extern "C" void kernel_launch(void* const* d_in, const int* in_sizes, int n_in,
                              void* d_out, int out_size, void* d_ws, size_t ws_size,
                              hipStream_t stream) {
    (void)in_sizes; (void)n_in; (void)out_size; (void)ws_size;
    const float* x  = (const float*)d_in[0];
    const float* rw = (const float*)d_in[1];
    const float* ew = (const float*)d_in[2];
    const float* eb = (const float*)d_in[3];
    float* out = (float*)d_out;
    float* ws  = (float*)d_ws;   // needs BB*EE*4 = 64 KB
    moe_fused<<<BB, 256, 0, stream>>>(x, rw, ew, eb, out, ws);
    loss_kernel<<<1, 256, 0, stream>>>(ws, out);
}

// Round 2
// 93.488 us; speedup vs baseline: 1.3005x; 1.3005x over previous
//
#include <hip/hip_runtime.h>

#define BB 2048
#define DD 4096
#define PP 64
#define KK 64
#define EE 8
#define C2 128

typedef __attribute__((ext_vector_type(8))) short short8;
typedef __attribute__((ext_vector_type(4))) float floatx4;

__device__ inline unsigned short f2bf(float f) {
    unsigned int u = __builtin_bit_cast(unsigned int, f);
    u += 0x7FFFu + ((u >> 16) & 1u);   // RNE round to bf16
    return (unsigned short)(u >> 16);
}

// One block per batch row b (256 threads, 4 waves).
//  phase 1: load x[b] (float4, coalesced) -> bf16 LDS patches + register col-sum partials
//  phase 2: wave 0: reduce col sums, 8 router dots via butterfly shuffles, argmax
//  phase 3: stage selected expert weights fp32->bf16 into LDS (aliases col-sum buffer)
//  phase 4: mfma 64x64 @ 64x128 bf16, epilogue (z+bias)^3 -> 2 logits -> softmax
__global__ __launch_bounds__(256) void moe_fused(
    const float* __restrict__ x, const float* __restrict__ rw,
    const float* __restrict__ ew, const float* __restrict__ eb,
    float* __restrict__ out, float* __restrict__ ws_sel)
{
    __shared__ __align__(16) unsigned short patb[64][72];   // bf16 patches, 144 B rows (16B mult)
    __shared__ __align__(16) unsigned char ubuf[128 * 72 * 2]; // phase1-2: cpart[16][64] f32; phase3+: wbf[128][72] bf16
    __shared__ float biasf[128];
    __shared__ float red0[4], red1[4];
    __shared__ float gate_s;
    __shared__ int idx_s;

    float (*cpart)[64]         = (float (*)[64])ubuf;
    unsigned short (*wbf)[72]  = (unsigned short (*)[72])ubuf;

    const int b = blockIdx.x;
    const int tid = threadIdx.x;

    // ---- phase 1: x load + bf16 convert + per-thread column partial sums
    {
        const float4* xb4 = (const float4*)(x + (size_t)b * DD);
        float c0 = 0.f, c1 = 0.f, c2 = 0.f, c3 = 0.f;
        #pragma unroll
        for (int j = 0; j < 4; ++j) {
            int idx = j * 256 + tid;         // float4 index within 1024
            float4 v = xb4[idx];
            int p = idx >> 4;                // j*16 + (tid>>4)
            int k = (idx & 15) << 2;         // fixed per thread across j
            ushort4 w4;
            w4.x = f2bf(v.x); w4.y = f2bf(v.y);
            w4.z = f2bf(v.z); w4.w = f2bf(v.w);
            *(ushort4*)&patb[p][k] = w4;     // 8 B aligned store
            c0 += v.x; c1 += v.y; c2 += v.z; c3 += v.w;
        }
        int m  = tid >> 4;
        int kq = (tid & 15) << 2;
        float4 cp; cp.x = c0; cp.y = c1; cp.z = c2; cp.w = c3;
        *(float4*)&cpart[m][kq] = cp;        // 16 B aligned (kq*4 mult of 16)
    }
    __syncthreads();

    // ---- phase 2: router (wave 0 only, fp32: argmax must match np ref)
    if (tid < 64) {
        float s = 0.f;
        #pragma unroll
        for (int m2 = 0; m2 < 16; ++m2) s += cpart[m2][tid];   // bank: 2 lanes/bank (free)
        float myg = 0.f; int myix = 0;
        #pragma unroll
        for (int e2 = 0; e2 < 8; ++e2) {
            float d = s * rw[e2 * KK + tid];
            d += __shfl_xor(d, 32); d += __shfl_xor(d, 16); d += __shfl_xor(d, 8);
            d += __shfl_xor(d, 4);  d += __shfl_xor(d, 2);  d += __shfl_xor(d, 1);
            // all 64 lanes now hold the full dot for expert e2
            if (tid == e2) ws_sel[b * 8 + e2] = d;            // stage for loss kernel
            if (e2 == 0 || d > myg) { myg = d; myix = e2; }   // strict >: first-max (np.argmax)
        }
        if (tid == 0) { gate_s = myg; idx_s = myix; }
        if (tid < 8)
            out[BB * 2 + b * 8 + tid] = (tid == myix && myg != 0.f) ? 1.f : 0.f; // select0
    }
    __syncthreads();

    const int e = idx_s;
    const float gate = gate_s;

    // ---- phase 3: stage selected expert weights fp32 -> bf16 (aliases cpart region) + bias
    {
        const float4* we4 = (const float4*)(ew + (size_t)e * (C2 * KK));
        #pragma unroll
        for (int j = 0; j < 8; ++j) {
            int idx = j * 256 + tid;         // float4 index within 2048
            float4 v = we4[idx];
            int c = idx >> 4;
            int k = (idx & 15) << 2;
            ushort4 w4;
            w4.x = f2bf(v.x); w4.y = f2bf(v.y);
            w4.z = f2bf(v.z); w4.w = f2bf(v.w);
            *(ushort4*)&wbf[c][k] = w4;
        }
        if (tid < 128) biasf[tid] = eb[e * C2 + tid];
    }
    __syncthreads();

    // ---- phase 4: D[p][c] = sum_k pat[p][k]*w[c][k] via mfma_f32_16x16x32_bf16
    const int w = tid >> 6;       // wave id -> 16-row M slice
    const int lane = tid & 63;
    const int r = lane & 15;
    const int q = lane >> 4;

    floatx4 acc[8];
    #pragma unroll
    for (int nt = 0; nt < 8; ++nt) acc[nt] = (floatx4){0.f, 0.f, 0.f, 0.f};

    #pragma unroll
    for (int kb = 0; kb < 2; ++kb) {
        const int k0 = kb * 32 + q * 8;
        short8 a = *(const short8*)&patb[w * 16 + r][k0];       // single ds_read_b128
        #pragma unroll
        for (int nt = 0; nt < 8; ++nt) {
            short8 bfr = *(const short8*)&wbf[nt * 16 + r][k0];
            acc[nt] = __builtin_amdgcn_mfma_f32_16x16x32_bf16(a, bfr, acc[nt], 0, 0, 0);
        }
    }

    // ---- epilogue: (z+bias)^3, halves c<64 (nt<4) / c>=64 (nt>=4)
    float h0 = 0.f, h1 = 0.f;
    #pragma unroll
    for (int nt = 0; nt < 8; ++nt) {
        float bs = biasf[nt * 16 + r];       // c = nt*16 + (lane&15)
        #pragma unroll
        for (int i = 0; i < 4; ++i) {
            float z = acc[nt][i] + bs;
            float z3 = z * z * z;
            if (nt < 4) h0 += z3; else h1 += z3;
        }
    }
    #pragma unroll
    for (int off = 32; off > 0; off >>= 1) {
        h0 += __shfl_down(h0, off);
        h1 += __shfl_down(h1, off);
    }
    if (lane == 0) { red0[w] = h0; red1[w] = h1; }
    __syncthreads();
    if (tid == 0) {
        float t0 = red0[0] + red0[1] + red0[2] + red0[3];
        float t1 = red1[0] + red1[1] + red1[2] + red1[3];
        float l0 = gate * t0, l1 = gate * t1;
        float m = fmaxf(l0, l1);
        float e0 = __expf(l0 - m), e1 = __expf(l1 - m);
        float inv = 1.f / (e0 + e1);
        out[b * 2 + 0] = e0 * inv;
        out[b * 2 + 1] = e1 * inv;
    }
}

// loss = E * sum_e (mean_b select[b,e]) * (count_b(argmax==e)/B) — shuffle reduce, no atomics
__global__ __launch_bounds__(256) void loss_kernel(
    const float* __restrict__ ws_sel, float* __restrict__ out)
{
    __shared__ float red[4][16];
    const int t = threadIdx.x;
    const int w = t >> 6, lane = t & 63;

    float p[8] = {0,0,0,0,0,0,0,0};
    float c[8] = {0,0,0,0,0,0,0,0};
    #pragma unroll
    for (int it = 0; it < BB / 256; ++it) {
        int b = it * 256 + t;
        const float4* row = (const float4*)(ws_sel + b * 8);
        float4 r0 = row[0], r1 = row[1];
        float v[8] = {r0.x, r0.y, r0.z, r0.w, r1.x, r1.y, r1.z, r1.w};
        float g = v[0]; int ix = 0;
        #pragma unroll
        for (int e2 = 1; e2 < 8; ++e2)
            if (v[e2] > g) { g = v[e2]; ix = e2; }   // strict >: first-max
        #pragma unroll
        for (int e2 = 0; e2 < 8; ++e2) p[e2] += v[e2];
        c[ix] += 1.f;
    }
    #pragma unroll
    for (int off = 32; off > 0; off >>= 1) {
        #pragma unroll
        for (int e2 = 0; e2 < 8; ++e2) {
            p[e2] += __shfl_xor(p[e2], off);
            c[e2] += __shfl_xor(c[e2], off);
        }
    }
    if (lane == 0) {
        #pragma unroll
        for (int e2 = 0; e2 < 8; ++e2) { red[w][e2] = p[e2]; red[w][8 + e2] = c[e2]; }
    }
    __syncthreads();
    if (t == 0) {
        float loss = 0.f;
        #pragma unroll
        for (int e2 = 0; e2 < 8; ++e2) {
            float sp = red[0][e2] + red[1][e2] + red[2][e2] + red[3][e2];
            float sc = red[0][8 + e2] + red[1][8 + e2] + red[2][8 + e2] + red[3][8 + e2];
            loss += (sp / (float)BB) * (sc / (float)BB);
        }
        out[BB * 2 + BB * 8] = loss * (float)EE;
    }
}

extern "C" void kernel_launch(void* const* d_in, const int* in_sizes, int n_in,
                              void* d_out, int out_size, void* d_ws, size_t ws_size,
                              hipStream_t stream) {
    (void)in_sizes; (void)n_in; (void)out_size; (void)ws_size;
    const float* x  = (const float*)d_in[0];
    const float* rw = (const float*)d_in[1];
    const float* ew = (const float*)d_in[2];
    const float* eb = (const float*)d_in[3];
    float* out = (float*)d_out;
    float* ws  = (float*)d_ws;   // needs BB*EE*4 = 64 KB
    moe_fused<<<BB, 256, 0, stream>>>(x, rw, ew, eb, out, ws);
    loss_kernel<<<1, 256, 0, stream>>>(ws, out);
}

// Round 3
// 92.912 us; speedup vs baseline: 1.3086x; 1.0062x over previous
//
#include <hip/hip_runtime.h>

#define BB 2048
#define DD 4096
#define PP 64
#define KK 64
#define EE 8
#define C2 128

typedef __attribute__((ext_vector_type(8))) short short8;
typedef __attribute__((ext_vector_type(4))) float floatx4;

__device__ inline unsigned short f2bf(float f) {          // RNE (prep kernel only)
    unsigned int u = __builtin_bit_cast(unsigned int, f);
    u += 0x7FFFu + ((u >> 16) & 1u);
    return (unsigned short)(u >> 16);
}
__device__ inline unsigned pack2_trunc(float lo, float hi) { // 2 bf16 (truncate) in 1 u32
    unsigned ul = __builtin_bit_cast(unsigned, lo);
    unsigned uh = __builtin_bit_cast(unsigned, hi);
    return (uh & 0xFFFF0000u) | (ul >> 16);
}

// ---- prep: expert weights fp32 -> bf16 (RNE) into ws. 65536 values.
__global__ __launch_bounds__(256) void prep_w(const float* __restrict__ ew,
                                              unsigned short* __restrict__ wbf) {
    int idx = blockIdx.x * 256 + threadIdx.x;             // 0..16383 float4s
    float4 v = ((const float4*)ew)[idx];
    ushort4 o;
    o.x = f2bf(v.x); o.y = f2bf(v.y); o.z = f2bf(v.z); o.w = f2bf(v.w);
    ((ushort4*)wbf)[idx] = o;
}

// ---- main: one wave per row. Zero LDS, zero barriers.
__global__ __launch_bounds__(256) void moe3(
    const float* __restrict__ x, const float* __restrict__ rw,
    const unsigned short* __restrict__ wbf, const float* __restrict__ eb,
    float* __restrict__ out, float* __restrict__ ws_sel)
{
    const int lane = threadIdx.x & 63;
    const int b = blockIdx.x * 4 + (threadIdx.x >> 6);    // one row per wave
    const int r = lane & 15, q = lane >> 4;
    const float* xb = x + (size_t)b * DD;

    // ---- load x in MFMA A-layout; col-sum partials in fp32; pack bf16 A-frags
    float ps[16];                                          // [kb*8+j]
    #pragma unroll
    for (int j = 0; j < 16; ++j) ps[j] = 0.f;
    short8 af[8];                                          // [mt*2+kb]
    #pragma unroll
    for (int mt = 0; mt < 4; ++mt) {
        #pragma unroll
        for (int kb = 0; kb < 2; ++kb) {
            const float* base = xb + (mt * 16 + r) * 64 + kb * 32 + q * 8;
            float4 v0 = *(const float4*)base;
            float4 v1 = *(const float4*)(base + 4);
            ps[kb*8+0] += v0.x; ps[kb*8+1] += v0.y; ps[kb*8+2] += v0.z; ps[kb*8+3] += v0.w;
            ps[kb*8+4] += v1.x; ps[kb*8+5] += v1.y; ps[kb*8+6] += v1.z; ps[kb*8+7] += v1.w;
            uint4 u;
            u.x = pack2_trunc(v0.x, v0.y); u.y = pack2_trunc(v0.z, v0.w);
            u.z = pack2_trunc(v1.x, v1.y); u.w = pack2_trunc(v1.z, v1.w);
            af[mt * 2 + kb] = __builtin_bit_cast(short8, u);
        }
    }
    // lane(q,r) now holds partial col sums over its 4 patch rows, for
    // k = kb*32 + q*8 + j. Full dot = reduce over all 64 lanes per expert.

    // ---- router (fp32; strict first-max argmax matches np)
    float d[8];
    #pragma unroll
    for (int e2 = 0; e2 < 8; ++e2) {
        const float* rwe = rw + e2 * KK;
        float4 a0 = *(const float4*)(rwe + q * 8);
        float4 a1 = *(const float4*)(rwe + q * 8 + 4);
        float4 b0 = *(const float4*)(rwe + 32 + q * 8);
        float4 b1 = *(const float4*)(rwe + 32 + q * 8 + 4);
        float t = ps[0]*a0.x + ps[1]*a0.y + ps[2]*a0.z + ps[3]*a0.w
                + ps[4]*a1.x + ps[5]*a1.y + ps[6]*a1.z + ps[7]*a1.w
                + ps[8]*b0.x + ps[9]*b0.y + ps[10]*b0.z + ps[11]*b0.w
                + ps[12]*b1.x + ps[13]*b1.y + ps[14]*b1.z + ps[15]*b1.w;
        t += __shfl_xor(t, 1);  t += __shfl_xor(t, 2);  t += __shfl_xor(t, 4);
        t += __shfl_xor(t, 8);  t += __shfl_xor(t, 16); t += __shfl_xor(t, 32);
        d[e2] = t;                                         // all lanes hold it
    }
    float gate = d[0]; int e = 0;
    #pragma unroll
    for (int e2 = 1; e2 < 8; ++e2)
        if (d[e2] > gate) { gate = d[e2]; e = e2; }

    if (lane == 0) {
        float4 s0 = make_float4(d[0], d[1], d[2], d[3]);
        float4 s1 = make_float4(d[4], d[5], d[6], d[7]);
        *(float4*)(ws_sel + b * 8)     = s0;               // staged for loss
        *(float4*)(ws_sel + b * 8 + 4) = s1;
        float on = (gate != 0.f) ? 1.f : 0.f;
        float4 o0 = make_float4(e==0?on:0.f, e==1?on:0.f, e==2?on:0.f, e==3?on:0.f);
        float4 o1 = make_float4(e==4?on:0.f, e==5?on:0.f, e==6?on:0.f, e==7?on:0.f);
        *(float4*)(out + BB * 2 + b * 8)     = o0;         // select0
        *(float4*)(out + BB * 2 + b * 8 + 4) = o1;
    }

    // ---- expert compute: D[p][c] via mfma, epilogue (z+bias)^3 fused per tile
    const unsigned short* we = wbf + (size_t)e * (C2 * KK);
    float h0 = 0.f, h1 = 0.f;
    #pragma unroll
    for (int nt = 0; nt < 8; ++nt) {
        float bs = eb[e * C2 + nt * 16 + r];               // c = nt*16 + (lane&15)
        const unsigned short* wr = we + (nt * 16 + r) * KK + q * 8;
        short8 bf0 = *(const short8*)wr;                   // kb=0, 16B aligned
        short8 bf1 = *(const short8*)(wr + 32);            // kb=1
        #pragma unroll
        for (int mt = 0; mt < 4; ++mt) {
            floatx4 acc = (floatx4){0.f, 0.f, 0.f, 0.f};
            acc = __builtin_amdgcn_mfma_f32_16x16x32_bf16(af[mt*2+0], bf0, acc, 0, 0, 0);
            acc = __builtin_amdgcn_mfma_f32_16x16x32_bf16(af[mt*2+1], bf1, acc, 0, 0, 0);
            float hh = 0.f;
            #pragma unroll
            for (int i = 0; i < 4; ++i) {
                float z = acc[i] + bs;
                hh = fmaf(z * z, z, hh);
            }
            if (nt < 4) h0 += hh; else h1 += hh;
        }
    }
    #pragma unroll
    for (int off = 1; off < 64; off <<= 1) {
        h0 += __shfl_xor(h0, off);
        h1 += __shfl_xor(h1, off);
    }
    if (lane == 0) {
        float l0 = gate * h0, l1 = gate * h1;
        float m = fmaxf(l0, l1);
        float e0 = __expf(l0 - m), e1 = __expf(l1 - m);
        float inv = 1.f / (e0 + e1);
        float2 o; o.x = e0 * inv; o.y = e1 * inv;
        *(float2*)(out + b * 2) = o;
    }
}

// loss = E * sum_e (mean_b select[b,e]) * (count_b(argmax==e)/B)
__global__ __launch_bounds__(256) void loss_kernel(
    const float* __restrict__ ws_sel, float* __restrict__ out)
{
    __shared__ float red[4][16];
    const int t = threadIdx.x;
    const int w = t >> 6, lane = t & 63;

    float p[8] = {0,0,0,0,0,0,0,0};
    float c[8] = {0,0,0,0,0,0,0,0};
    #pragma unroll
    for (int it = 0; it < BB / 256; ++it) {
        int b = it * 256 + t;
        const float4* row = (const float4*)(ws_sel + b * 8);
        float4 r0 = row[0], r1 = row[1];
        float v[8] = {r0.x, r0.y, r0.z, r0.w, r1.x, r1.y, r1.z, r1.w};
        float g = v[0]; int ix = 0;
        #pragma unroll
        for (int e2 = 1; e2 < 8; ++e2)
            if (v[e2] > g) { g = v[e2]; ix = e2; }          // strict >: first-max
        #pragma unroll
        for (int e2 = 0; e2 < 8; ++e2) p[e2] += v[e2];
        c[ix] += 1.f;
    }
    #pragma unroll
    for (int off = 32; off > 0; off >>= 1) {
        #pragma unroll
        for (int e2 = 0; e2 < 8; ++e2) {
            p[e2] += __shfl_xor(p[e2], off);
            c[e2] += __shfl_xor(c[e2], off);
        }
    }
    if (lane == 0) {
        #pragma unroll
        for (int e2 = 0; e2 < 8; ++e2) { red[w][e2] = p[e2]; red[w][8 + e2] = c[e2]; }
    }
    __syncthreads();
    if (t == 0) {
        float loss = 0.f;
        #pragma unroll
        for (int e2 = 0; e2 < 8; ++e2) {
            float sp = red[0][e2] + red[1][e2] + red[2][e2] + red[3][e2];
            float sc = red[0][8 + e2] + red[1][8 + e2] + red[2][8 + e2] + red[3][8 + e2];
            loss += (sp / (float)BB) * (sc / (float)BB);
        }
        out[BB * 2 + BB * 8] = loss * (float)EE;
    }
}

extern "C" void kernel_launch(void* const* d_in, const int* in_sizes, int n_in,
                              void* d_out, int out_size, void* d_ws, size_t ws_size,
                              hipStream_t stream) {
    (void)in_sizes; (void)n_in; (void)out_size; (void)ws_size;
    const float* x  = (const float*)d_in[0];
    const float* rw = (const float*)d_in[1];
    const float* ew = (const float*)d_in[2];
    const float* eb = (const float*)d_in[3];
    float* out = (float*)d_out;
    float* ws_sel = (float*)d_ws;                              // 64 KB: per-row selects
    unsigned short* wbf = (unsigned short*)((char*)d_ws + BB * EE * 4); // 128 KB bf16 weights

    prep_w<<<64, 256, 0, stream>>>(ew, wbf);
    moe3<<<BB / 4, 256, 0, stream>>>(x, rw, wbf, eb, out, ws_sel);
    loss_kernel<<<1, 256, 0, stream>>>(ws_sel, out);
}